// Round 4
// baseline (55.057 us; speedup 1.0000x reference)
//
#include <hip/hip_runtime.h>

// BurstCoding: out[b,t,s] = ((t % period) < burst_length) && ((t / period) < floor(clip(x[b,s],0,1)*max_bursts))
// x: [B=16, 3, 224, 224] f32, out: [B, T=32, 3, 224, 224] f32.
//
// Memory-bound: ~301 MB write + ~10 MB read. Rounds 1-2: 53.7 us (5.9 TB/s)
// for both per-input and per-plane mappings -> access pattern not the lever.
// This round: non-temporal streaming stores (output is write-once, never
// re-read; bypass L2 write-allocate) + 32 B per thread for store ILP.
// Target: harness fillBuffer rate (~6.9 TB/s on this chip).
//
// NOTE: __builtin_nontemporal_store requires a clang ext_vector type, not
// HIP's float4 class -> use f32x4 below.
//
// Predicate simplification (exact): bidx < floor(clamp(x,0,1)*maxb)
//   <=> clamp(x,0,1)*maxb >= bidx+1   (y>=0, integer rhs)

typedef float f32x4 __attribute__((ext_vector_type(4)));

__global__ __launch_bounds__(256) void burst_coding_kernel(
    const float* __restrict__ x, float* __restrict__ out,
    const int* __restrict__ p_bl, const int* __restrict__ p_ibi,
    int T, int S4)
{
    const int bl     = *p_bl;            // burst_length (scalar broadcast)
    const int period = bl + *p_ibi;      // burst_length + interburst_interval
    const int maxb   = T / period;       // max_bursts

    const int bt   = blockIdx.y;         // b*T + t
    const int t    = bt % T;
    const int b    = bt / T;
    const int tm   = t % period;
    const int bidx = t / period;

    // two float4s per thread, 512 float4s per block
    const int s4a = blockIdx.x * (blockDim.x * 2) + threadIdx.x;
    const int s4b = s4a + blockDim.x;

    f32x4* op = reinterpret_cast<f32x4*>(out) + (long)bt * S4;

    if (tm >= bl || bidx >= maxb) {
        // inactive plane: all zeros, no x read — pure streaming store
        const f32x4 z = {0.f, 0.f, 0.f, 0.f};
        if (s4a < S4) __builtin_nontemporal_store(z, op + s4a);
        if (s4b < S4) __builtin_nontemporal_store(z, op + s4b);
        return;
    }

    const float mbf  = (float)maxb;
    const float bthr = (float)(bidx + 1);
    const f32x4* xp  = reinterpret_cast<const f32x4*>(x) + (long)b * S4;

    if (s4a < S4) {
        const f32x4 xv = xp[s4a];
        f32x4 v;
        v.x = (fminf(fmaxf(xv.x, 0.f), 1.f) * mbf >= bthr) ? 1.f : 0.f;
        v.y = (fminf(fmaxf(xv.y, 0.f), 1.f) * mbf >= bthr) ? 1.f : 0.f;
        v.z = (fminf(fmaxf(xv.z, 0.f), 1.f) * mbf >= bthr) ? 1.f : 0.f;
        v.w = (fminf(fmaxf(xv.w, 0.f), 1.f) * mbf >= bthr) ? 1.f : 0.f;
        __builtin_nontemporal_store(v, op + s4a);
    }
    if (s4b < S4) {
        const f32x4 xv = xp[s4b];
        f32x4 v;
        v.x = (fminf(fmaxf(xv.x, 0.f), 1.f) * mbf >= bthr) ? 1.f : 0.f;
        v.y = (fminf(fmaxf(xv.y, 0.f), 1.f) * mbf >= bthr) ? 1.f : 0.f;
        v.z = (fminf(fmaxf(xv.z, 0.f), 1.f) * mbf >= bthr) ? 1.f : 0.f;
        v.w = (fminf(fmaxf(xv.w, 0.f), 1.f) * mbf >= bthr) ? 1.f : 0.f;
        __builtin_nontemporal_store(v, op + s4b);
    }
}

extern "C" void kernel_launch(void* const* d_in, const int* in_sizes, int n_in,
                              void* d_out, int out_size, void* d_ws, size_t ws_size,
                              hipStream_t stream) {
    const float* x   = (const float*)d_in[0];
    // d_in[1] = timesteps (derived on host from sizes instead)
    const int* p_bl  = (const int*)d_in[2];  // burst_length
    const int* p_ibi = (const int*)d_in[3];  // interburst_interval
    float* out = (float*)d_out;

    const long N  = (long)in_sizes[0];          // B * S
    const int  T  = (int)((long)out_size / N);  // = 32
    const int  S  = 3 * 224 * 224;              // spatial elems per batch (reference setup)
    const int  S4 = S / 4;                      // 37632 float4 per plane
    const int  B  = (int)(N / S);               // 16

    const int threads = 256;
    const int f4_per_block = threads * 2;       // 512
    dim3 grid((S4 + f4_per_block - 1) / f4_per_block,  // 74 blocks along spatial
              (unsigned)(B * T));                      // 512 planes

    burst_coding_kernel<<<grid, dim3(threads), 0, stream>>>(
        x, out, p_bl, p_ibi, T, S4);
}